// Round 1
// 240.687 us; speedup vs baseline: 1.2052x; 1.2052x over previous
//
#include <hip/hip_runtime.h>
#include <hip/hip_bf16.h>
#include <math.h>

#define DIM 64

typedef __attribute__((ext_vector_type(8))) short bf16x8;
typedef __attribute__((ext_vector_type(4))) float f32x4;
typedef unsigned short ushort_t;

__device__ __forceinline__ float silu_f(float x) {
    float e = __expf(-x);
    return x * __builtin_amdgcn_rcpf(1.0f + e);
}
// fast fp32->bf16 RNE (finite inputs)
__device__ __forceinline__ unsigned short f2bf_fast(float x) {
    unsigned u = __builtin_bit_cast(unsigned, x);
    u += 0x7FFFu + ((u >> 16) & 1u);
    return (unsigned short)(u >> 16);
}
// wave-internal LDS sync: lgkmcnt(0) only — no s_barrier, no vmcnt drain
__device__ __forceinline__ void wave_sync() {
    __builtin_amdgcn_wave_barrier();
    __builtin_amdgcn_s_waitcnt(0xC07F);
    __builtin_amdgcn_wave_barrier();
}

// ---------------- prep: u[k] = Wv[k,:]·wF ; c0 = bv·wF + bF ----------------
__global__ __launch_bounds__(64) void k_prep(
    const float* __restrict__ Wv, const float* __restrict__ bv,
    const float* __restrict__ wF, const float* __restrict__ bF,
    float* __restrict__ u, float* __restrict__ c0)
{
    int lane = threadIdx.x;
    float acc = 0.f;
    for (int n = 0; n < 64; ++n) acc += Wv[lane * 64 + n] * wF[n];
    u[lane] = acc;
    float p = bv[lane] * wF[lane];
    #pragma unroll
    for (int off = 32; off; off >>= 1) p += __shfl_xor(p, off, 64);
    if (lane == 0) c0[0] = p + bF[0];
}

// ---------------- k_proj: MFMA GEMM for Q, K (bf16 out) + gate ----------------
__global__ __launch_bounds__(256) void k_proj_mfma(
    const float* __restrict__ x,
    const float* __restrict__ Wq, const float* __restrict__ bq,
    const float* __restrict__ Wk, const float* __restrict__ bk,
    const float* __restrict__ u, const float* __restrict__ c0p,
    ushort_t* __restrict__ Qh, ushort_t* __restrict__ Kh,
    float* __restrict__ gate, int nNodes, int nTiles)
{
    const int tid = threadIdx.x;
    const int lane = tid & 63;
    const int w = tid >> 6;
    const int lanen = lane & 15;
    const int q = lane >> 4;

    bf16x8 Bq[2][4], Bk[2][4];
    #pragma unroll
    for (int c = 0; c < 2; ++c)
        #pragma unroll
        for (int t = 0; t < 4; ++t) {
            bf16x8 vq, vk;
            #pragma unroll
            for (int j = 0; j < 8; ++j) {
                int idx = (c * 32 + q * 8 + j) * 64 + t * 16 + lanen;
                vq[j] = (short)f2bf_fast(Wq[idx]);
                vk[j] = (short)f2bf_fast(Wk[idx]);
            }
            Bq[c][t] = vq; Bk[c][t] = vk;
        }
    float bqv[4], bkv[4];
    #pragma unroll
    for (int t = 0; t < 4; ++t) { bqv[t] = bq[t * 16 + lanen]; bkv[t] = bk[t * 16 + lanen]; }
    float ur0[8], ur1[8];
    #pragma unroll
    for (int j = 0; j < 8; ++j) { ur0[j] = u[q * 8 + j]; ur1[j] = u[32 + q * 8 + j]; }
    const float c0 = c0p[0];

    const int waveId = blockIdx.x * 4 + w;
    const int wstride = gridDim.x * 4;

    for (int tile = waveId; tile < nTiles; tile += wstride) {
        int node0 = tile * 16;
        int nodeA = node0 + lanen;
        int nodeC = (nodeA < nNodes) ? nodeA : (nNodes - 1);
        const float4* xr = (const float4*)(x + (size_t)nodeC * 64);
        float4 xa = xr[q * 2], xb = xr[q * 2 + 1];
        float4 xc = xr[8 + q * 2], xd = xr[8 + q * 2 + 1];

        float g = xa.x * ur0[0] + xa.y * ur0[1] + xa.z * ur0[2] + xa.w * ur0[3]
                + xb.x * ur0[4] + xb.y * ur0[5] + xb.z * ur0[6] + xb.w * ur0[7]
                + xc.x * ur1[0] + xc.y * ur1[1] + xc.z * ur1[2] + xc.w * ur1[3]
                + xd.x * ur1[4] + xd.y * ur1[5] + xd.z * ur1[6] + xd.w * ur1[7];
        g += __shfl_xor(g, 16);
        g += __shfl_xor(g, 32);

        bf16x8 a0, a1;
        a0[0] = (short)f2bf_fast(xa.x); a0[1] = (short)f2bf_fast(xa.y);
        a0[2] = (short)f2bf_fast(xa.z); a0[3] = (short)f2bf_fast(xa.w);
        a0[4] = (short)f2bf_fast(xb.x); a0[5] = (short)f2bf_fast(xb.y);
        a0[6] = (short)f2bf_fast(xb.z); a0[7] = (short)f2bf_fast(xb.w);
        a1[0] = (short)f2bf_fast(xc.x); a1[1] = (short)f2bf_fast(xc.y);
        a1[2] = (short)f2bf_fast(xc.z); a1[3] = (short)f2bf_fast(xc.w);
        a1[4] = (short)f2bf_fast(xd.x); a1[5] = (short)f2bf_fast(xd.y);
        a1[6] = (short)f2bf_fast(xd.z); a1[7] = (short)f2bf_fast(xd.w);

        f32x4 accq[4] = {{0,0,0,0},{0,0,0,0},{0,0,0,0},{0,0,0,0}};
        f32x4 acck[4] = {{0,0,0,0},{0,0,0,0},{0,0,0,0},{0,0,0,0}};
        #pragma unroll
        for (int t = 0; t < 4; ++t) {
            accq[t] = __builtin_amdgcn_mfma_f32_16x16x32_bf16(a0, Bq[0][t], accq[t], 0, 0, 0);
            accq[t] = __builtin_amdgcn_mfma_f32_16x16x32_bf16(a1, Bq[1][t], accq[t], 0, 0, 0);
            acck[t] = __builtin_amdgcn_mfma_f32_16x16x32_bf16(a0, Bk[0][t], acck[t], 0, 0, 0);
            acck[t] = __builtin_amdgcn_mfma_f32_16x16x32_bf16(a1, Bk[1][t], acck[t], 0, 0, 0);
        }

        #pragma unroll
        for (int t = 0; t < 4; ++t)
            #pragma unroll
            for (int r = 0; r < 4; ++r) {
                int node = node0 + q * 4 + r;
                if (node < nNodes) {
                    size_t o = (size_t)node * 64 + t * 16 + lanen;
                    Qh[o] = f2bf_fast(accq[t][r] + bqv[t]);
                    Kh[o] = f2bf_fast(acck[t][r] + bkv[t]);
                }
            }
        if (q == 0 && nodeA < nNodes) gate[nodeA] = g + c0;
    }
}

// ---------------- edge kernel: MLP bias + MFMA score + atomic segment-sums ----------------
// Layout: edge = lanen (lane&15), k-chunk = q (lane>>4).
//   Q/K gathers are exact 16x16x32 A/B fragments -> score dot = diag(Q @ K^T) via 2 MFMAs.
//   h1 computed per-lane directly in A-frag layout (edge lanen, dims q*8+j / 32+q*8+j).
//   Output: one global_atomic_add_f32 per lane per tile into out4[j] = {sum evg*vec, sum ev}.
__global__ __launch_bounds__(256) void k_edge_mfma(
    const int* __restrict__ ei, const int* __restrict__ ej,
    const ushort_t* __restrict__ Qh, const ushort_t* __restrict__ Kh,
    const float* __restrict__ gate, const float* __restrict__ edge_vec,
    const float* __restrict__ W1, const float* __restrict__ b1,
    const float* __restrict__ W2, const float* __restrict__ b2,
    const float* __restrict__ W3, const float* __restrict__ b3,
    float* __restrict__ out4, int nEdges, long nTiles)
{
    // W1 columns, slot-swizzled (slot = d + (d>>3)) so the 4 q-group b128 reads
    // per instruction land in disjoint bank quads.
    __shared__ __align__(16) float4 sW1v[72];
    __shared__ float sB1[64];
    __shared__ float sBias[4][16];
    __shared__ float sDot[4][16];

    const int tid = threadIdx.x;
    const int lane = tid & 63;
    const int w = tid >> 6;
    const int lanen = lane & 15;
    const int q = lane >> 4;

    if (tid < 64) {
        int slot = tid + (tid >> 3);
        sW1v[slot] = make_float4(W1[tid], W1[64 + tid], W1[128 + tid], W1[192 + tid]);
        sB1[tid] = b1[tid];
    }

    bf16x8 Bfrag[2][4];
    #pragma unroll
    for (int c = 0; c < 2; ++c)
        #pragma unroll
        for (int t = 0; t < 4; ++t) {
            bf16x8 v;
            #pragma unroll
            for (int j = 0; j < 8; ++j)
                v[j] = (short)f2bf_fast(W2[(c * 32 + q * 8 + j) * 64 + t * 16 + lanen]);
            Bfrag[c][t] = v;
        }
    float b2r[4], w3r[4];
    #pragma unroll
    for (int t = 0; t < 4; ++t) { b2r[t] = b2[t * 16 + lanen]; w3r[t] = W3[t * 16 + lanen]; }
    const float b3r = b3[0];
    __syncthreads();

    const long wstride = (long)gridDim.x * 4;
    const long t0 = (long)blockIdx.x * 4 + w;

    auto idx_of = [&](long tile, int& ii, int& jj) {
        long es = tile * 16 + lanen;
        long esc = (es < nEdges) ? es : (long)(nEdges - 1);
        ii = ei[esc]; jj = ej[esc];
    };
    auto gather = [&](long tile, int ii, int jj,
                      bf16x8& A, bf16x8& B, bf16x8& C, bf16x8& D, float& G, float4& AT) {
        const bf16x8* qp = (const bf16x8*)(Qh + (size_t)jj * 64);
        A = qp[q]; B = qp[4 + q];
        const bf16x8* kp = (const bf16x8*)(Kh + (size_t)ii * 64);
        C = kp[q]; D = kp[4 + q];
        G = gate[ii];
        long em = tile * 16 + lanen;
        long emc = (em < nEdges) ? em : (long)(nEdges - 1);
        float ax = edge_vec[emc * 3 + 0];
        float ay = edge_vec[emc * 3 + 1];
        float az = edge_vec[emc * 3 + 2];
        AT = make_float4(ax, ay, az, sqrtf(ax * ax + ay * ay + az * az));
    };

    int iC, jC, iN, jN;
    idx_of(t0, iC, jC);
    idx_of(t0 + wstride, iN, jN);
    bf16x8 qa = {}, qb = {}, ka = {}, kb = {};
    float gte = 0.f;
    float4 attr = make_float4(0.f, 0.f, 0.f, 0.f);
    gather(t0, iC, jC, qa, qb, ka, kb, gte, attr);

    for (long tile = t0; tile < nTiles; tile += wstride) {
        // ---- layer1 directly into A-frag registers (fp32 math, RNE bf16 pack) ----
        int pw0[4], pw1[4];
        #pragma unroll
        for (int jj = 0; jj < 4; ++jj) {
            int d0 = q * 8 + 2 * jj;
            float4 cA = sW1v[d0 + q];
            float4 cB = sW1v[d0 + 1 + q];
            float4 cC = sW1v[d0 + 32 + q + 4];
            float4 cD = sW1v[d0 + 33 + q + 4];
            float p0 = sB1[d0]      + attr.x*cA.x + attr.y*cA.y + attr.z*cA.z + attr.w*cA.w;
            float p1 = sB1[d0 + 1]  + attr.x*cB.x + attr.y*cB.y + attr.z*cB.z + attr.w*cB.w;
            float p2 = sB1[d0 + 32] + attr.x*cC.x + attr.y*cC.y + attr.z*cC.z + attr.w*cC.w;
            float p3 = sB1[d0 + 33] + attr.x*cD.x + attr.y*cD.y + attr.z*cD.z + attr.w*cD.w;
            float h0 = silu_f(p0), h1v = silu_f(p1), h2v = silu_f(p2), h3v = silu_f(p3);
            int r0, r1;
            asm("v_cvt_pk_bf16_f32 %0, %1, %2" : "=v"(r0) : "v"(h0), "v"(h1v));
            asm("v_cvt_pk_bf16_f32 %0, %1, %2" : "=v"(r1) : "v"(h2v), "v"(h3v));
            pw0[jj] = r0; pw1[jj] = r1;
        }
        bf16x8 a0 = __builtin_bit_cast(bf16x8, make_int4(pw0[0], pw0[1], pw0[2], pw0[3]));
        bf16x8 a1 = __builtin_bit_cast(bf16x8, make_int4(pw1[0], pw1[1], pw1[2], pw1[3]));

        // ---- Q.K dot = diagonal of Q @ K^T via MFMA (matrix pipe is idle) ----
        f32x4 accd = {0.f, 0.f, 0.f, 0.f};
        accd = __builtin_amdgcn_mfma_f32_16x16x32_bf16(qa, ka, accd, 0, 0, 0);
        accd = __builtin_amdgcn_mfma_f32_16x16x32_bf16(qb, kb, accd, 0, 0, 0);

        // ---- layer2 GEMM ----
        f32x4 acc[4] = {{0,0,0,0},{0,0,0,0},{0,0,0,0},{0,0,0,0}};
        #pragma unroll
        for (int t = 0; t < 4; ++t) {
            acc[t] = __builtin_amdgcn_mfma_f32_16x16x32_bf16(a0, Bfrag[0][t], acc[t], 0, 0, 0);
            acc[t] = __builtin_amdgcn_mfma_f32_16x16x32_bf16(a1, Bfrag[1][t], acc[t], 0, 0, 0);
        }

        // ---- 1-ahead prefetch ----
        int iF, jF;
        idx_of(tile + 2 * wstride, iF, jF);
        bf16x8 qa2 = {}, qb2 = {}, ka2 = {}, kb2 = {};
        float gte2 = 0.f;
        float4 attr2 = make_float4(0.f, 0.f, 0.f, 0.f);
        gather(tile + wstride, iN, jN, qa2, qb2, ka2, kb2, gte2, attr2);

        // ---- diag extract -> sDot (lane ((e>>2)<<4)|e holds D[e][e] in reg e&3) ----
        if (q == (lanen >> 2)) {
            int rsel = lanen & 3;
            float d = accd[0];
            d = (rsel == 1) ? accd[1] : d;
            d = (rsel == 2) ? accd[2] : d;
            d = (rsel == 3) ? accd[3] : d;
            sDot[w][lanen] = d;
        }

        // ---- layer3 reduce -> sBias ----
        float part[4] = {0.f, 0.f, 0.f, 0.f};
        #pragma unroll
        for (int t = 0; t < 4; ++t)
            #pragma unroll
            for (int r = 0; r < 4; ++r)
                part[r] += silu_f(acc[t][r] + b2r[t]) * w3r[t];
        #pragma unroll
        for (int r = 0; r < 4; ++r) {
            part[r] += __shfl_xor(part[r], 1);
            part[r] += __shfl_xor(part[r], 2);
            part[r] += __shfl_xor(part[r], 4);
            part[r] += __shfl_xor(part[r], 8);
        }
        if (lanen == 0)
            *(float4*)&sBias[w][q * 4] = make_float4(part[0], part[1], part[2], part[3]);

        wave_sync();   // sBias/sDot visible

        // ---- max-free softmax numer/denom, fire-and-forget atomics ----
        float sc = sDot[w][lanen] * 0.125f + sBias[w][lanen] + b3r;
        float ev = __expf(sc);
        long eC = tile * 16 + lanen;
        if (eC < nEdges) {
            float comp = (q == 0) ? attr.x : (q == 1) ? attr.y : attr.z;
            float val = (q == 3) ? ev : ev * gte * comp;
            atomicAdd(out4 + (size_t)jC * 4 + q, val);
        }

        wave_sync();   // WAR: reads retired before next iter's LDS writes

        iC = iN; jC = jN; iN = iF; jN = jF;
        qa = qa2; qb = qb2; ka = ka2; kb = kb2; gte = gte2; attr = attr2;
    }
}

// ---------------- final divide: out = num / (den + 1e-16) ----------------
__global__ __launch_bounds__(256) void k_div(
    const float4* __restrict__ out4, float* __restrict__ out, int nNodes)
{
    int j = blockIdx.x * 256 + threadIdx.x;
    if (j >= nNodes) return;
    float4 v = out4[j];
    float inv = 1.0f / (v.w + 1e-16f);
    out[(size_t)j * 3 + 0] = v.x * inv;
    out[(size_t)j * 3 + 1] = v.y * inv;
    out[(size_t)j * 3 + 2] = v.z * inv;
}

extern "C" void kernel_launch(void* const* d_in, const int* in_sizes, int n_in,
                              void* d_out, int out_size, void* d_ws, size_t ws_size,
                              hipStream_t stream)
{
    const float* x        = (const float*)d_in[0];
    const float* edge_vec = (const float*)d_in[1];
    const float* Wq = (const float*)d_in[2];
    const float* bq = (const float*)d_in[3];
    const float* Wk = (const float*)d_in[4];
    const float* bk = (const float*)d_in[5];
    const float* Wv = (const float*)d_in[6];
    const float* bv = (const float*)d_in[7];
    const float* W1 = (const float*)d_in[8];
    const float* b1 = (const float*)d_in[9];
    const float* W2 = (const float*)d_in[10];
    const float* b2 = (const float*)d_in[11];
    const float* W3 = (const float*)d_in[12];
    const float* b3 = (const float*)d_in[13];
    const float* wF = (const float*)d_in[14];
    const float* bF = (const float*)d_in[15];
    const int*   eidx = (const int*)d_in[16];

    int nNodes = in_sizes[0] / DIM;
    int nEdges = in_sizes[16] / 2;
    const int* ei = eidx;
    const int* ej = eidx + nEdges;

    // ws layout
    char* p = (char*)d_ws;
    ushort_t* Qh = (ushort_t*)p;
    ushort_t* Kh = Qh + (size_t)nNodes * DIM;
    p += (size_t)nNodes * DIM * 2 * sizeof(ushort_t);
    float* gate = (float*)p;  p += (size_t)nNodes * sizeof(float);
    float* out4 = (float*)p;  p += (size_t)nNodes * 4 * sizeof(float);
    float* u = (float*)p;     p += 64 * sizeof(float);
    float* c0 = (float*)p;    p += 64 * sizeof(float);

    float* out = (float*)d_out;
    hipMemsetAsync(out4, 0, (size_t)nNodes * 4 * sizeof(float), stream);

    k_prep<<<1, 64, 0, stream>>>(Wv, bv, wF, bF, u, c0);

    int nTilesN = (nNodes + 15) / 16;
    k_proj_mfma<<<512, 256, 0, stream>>>(x, Wq, bq, Wk, bk, u, c0,
                                         Qh, Kh, gate, nNodes, nTilesN);

    long nTilesE = (nEdges + 15) / 16;
    k_edge_mfma<<<2048, 256, 0, stream>>>(ei, ej, Qh, Kh, gate, edge_vec,
                                          W1, b1, W2, b2, W3, b3,
                                          out4, nEdges, nTilesE);

    int nBn = (nNodes + 255) / 256;
    k_div<<<nBn, 256, 0, stream>>>((const float4*)out4, out, nNodes);
}

// Round 2
// 239.871 us; speedup vs baseline: 1.2093x; 1.0034x over previous
//
#include <hip/hip_runtime.h>
#include <hip/hip_bf16.h>
#include <math.h>

#define DIM 64

typedef __attribute__((ext_vector_type(8))) short bf16x8;
typedef __attribute__((ext_vector_type(4))) float f32x4;
typedef unsigned short ushort_t;

__device__ __forceinline__ float silu_f(float x) {
    float e = __expf(-x);
    return x * __builtin_amdgcn_rcpf(1.0f + e);
}
// fast fp32->bf16 RNE (finite inputs)
__device__ __forceinline__ unsigned short f2bf_fast(float x) {
    unsigned u = __builtin_bit_cast(unsigned, x);
    u += 0x7FFFu + ((u >> 16) & 1u);
    return (unsigned short)(u >> 16);
}

// ---------------- k_proj: MFMA GEMM for Q, K (bf16 out) + gate + fused prep + out4 zero ----------------
__global__ __launch_bounds__(256) void k_proj_mfma(
    const float* __restrict__ x,
    const float* __restrict__ Wq, const float* __restrict__ bq,
    const float* __restrict__ Wk, const float* __restrict__ bk,
    const float* __restrict__ Wv, const float* __restrict__ bv,
    const float* __restrict__ wF, const float* __restrict__ bF,
    ushort_t* __restrict__ Qh, ushort_t* __restrict__ Kh,
    float* __restrict__ gate, float* __restrict__ out4,
    int nNodes, int nTiles)
{
    const int tid = threadIdx.x;
    const int lane = tid & 63;
    const int w = tid >> 6;
    const int lanen = lane & 15;
    const int q = lane >> 4;

    // --- fused prep: u[d] = Wv[d,:]·wF (d = lane), c0 = bv·wF + bF ---
    float accu = 0.f;
    #pragma unroll
    for (int n = 0; n < 64; ++n) accu = fmaf(Wv[lane * 64 + n], wF[n], accu);
    float pc = bv[lane] * wF[lane];
    #pragma unroll
    for (int off = 32; off; off >>= 1) pc += __shfl_xor(pc, off, 64);
    const float c0 = pc + bF[0];
    const int ubits = __builtin_bit_cast(int, accu);
    float ur0[8], ur1[8];
    #pragma unroll
    for (int j = 0; j < 8; ++j) {
        ur0[j] = __builtin_bit_cast(float, __builtin_amdgcn_ds_bpermute((q * 8 + j) * 4, ubits));
        ur1[j] = __builtin_bit_cast(float, __builtin_amdgcn_ds_bpermute((32 + q * 8 + j) * 4, ubits));
    }

    bf16x8 Bq[2][4], Bk[2][4];
    #pragma unroll
    for (int c = 0; c < 2; ++c)
        #pragma unroll
        for (int t = 0; t < 4; ++t) {
            bf16x8 vq, vk;
            #pragma unroll
            for (int j = 0; j < 8; ++j) {
                int idx = (c * 32 + q * 8 + j) * 64 + t * 16 + lanen;
                vq[j] = (short)f2bf_fast(Wq[idx]);
                vk[j] = (short)f2bf_fast(Wk[idx]);
            }
            Bq[c][t] = vq; Bk[c][t] = vk;
        }
    float bqv[4], bkv[4];
    #pragma unroll
    for (int t = 0; t < 4; ++t) { bqv[t] = bq[t * 16 + lanen]; bkv[t] = bk[t * 16 + lanen]; }

    const int waveId = blockIdx.x * 4 + w;
    const int wstride = gridDim.x * 4;

    for (int tile = waveId; tile < nTiles; tile += wstride) {
        int node0 = tile * 16;
        int nodeA = node0 + lanen;
        int nodeC = (nodeA < nNodes) ? nodeA : (nNodes - 1);
        const float4* xr = (const float4*)(x + (size_t)nodeC * 64);
        float4 xa = xr[q * 2], xb = xr[q * 2 + 1];
        float4 xc = xr[8 + q * 2], xd = xr[8 + q * 2 + 1];

        float g = xa.x * ur0[0] + xa.y * ur0[1] + xa.z * ur0[2] + xa.w * ur0[3]
                + xb.x * ur0[4] + xb.y * ur0[5] + xb.z * ur0[6] + xb.w * ur0[7]
                + xc.x * ur1[0] + xc.y * ur1[1] + xc.z * ur1[2] + xc.w * ur1[3]
                + xd.x * ur1[4] + xd.y * ur1[5] + xd.z * ur1[6] + xd.w * ur1[7];
        g += __shfl_xor(g, 16);
        g += __shfl_xor(g, 32);

        bf16x8 a0, a1;
        a0[0] = (short)f2bf_fast(xa.x); a0[1] = (short)f2bf_fast(xa.y);
        a0[2] = (short)f2bf_fast(xa.z); a0[3] = (short)f2bf_fast(xa.w);
        a0[4] = (short)f2bf_fast(xb.x); a0[5] = (short)f2bf_fast(xb.y);
        a0[6] = (short)f2bf_fast(xb.z); a0[7] = (short)f2bf_fast(xb.w);
        a1[0] = (short)f2bf_fast(xc.x); a1[1] = (short)f2bf_fast(xc.y);
        a1[2] = (short)f2bf_fast(xc.z); a1[3] = (short)f2bf_fast(xc.w);
        a1[4] = (short)f2bf_fast(xd.x); a1[5] = (short)f2bf_fast(xd.y);
        a1[6] = (short)f2bf_fast(xd.z); a1[7] = (short)f2bf_fast(xd.w);

        f32x4 accq[4] = {{0,0,0,0},{0,0,0,0},{0,0,0,0},{0,0,0,0}};
        f32x4 acck[4] = {{0,0,0,0},{0,0,0,0},{0,0,0,0},{0,0,0,0}};
        #pragma unroll
        for (int t = 0; t < 4; ++t) {
            accq[t] = __builtin_amdgcn_mfma_f32_16x16x32_bf16(a0, Bq[0][t], accq[t], 0, 0, 0);
            accq[t] = __builtin_amdgcn_mfma_f32_16x16x32_bf16(a1, Bq[1][t], accq[t], 0, 0, 0);
            acck[t] = __builtin_amdgcn_mfma_f32_16x16x32_bf16(a0, Bk[0][t], acck[t], 0, 0, 0);
            acck[t] = __builtin_amdgcn_mfma_f32_16x16x32_bf16(a1, Bk[1][t], acck[t], 0, 0, 0);
        }

        #pragma unroll
        for (int t = 0; t < 4; ++t)
            #pragma unroll
            for (int r = 0; r < 4; ++r) {
                int node = node0 + q * 4 + r;
                if (node < nNodes) {
                    size_t o = (size_t)node * 64 + t * 16 + lanen;
                    Qh[o] = f2bf_fast(accq[t][r] + bqv[t]);
                    Kh[o] = f2bf_fast(acck[t][r] + bkv[t]);
                }
            }
        if (nodeA < nNodes) {
            if (q == 0) gate[nodeA] = g + c0;
            if (q == 1) *(float4*)(out4 + (size_t)nodeA * 4) = make_float4(0.f, 0.f, 0.f, 0.f);
        }
    }
}

// ---------------- edge kernel: MLP bias + MFMA score + atomic segment-sums ----------------
// Layout: edge = lanen (lane&15), k-chunk = q (lane>>4).
//   Q/K gathers are exact 16x16x32 A/B fragments -> score dot = diag(Q @ K^T) via 2 MFMAs.
//   h1 computed per-lane directly in A-frag layout (edge lanen, dims q*8+j / 32+q*8+j).
//   Score routing: lanes with q==lanen>>2 natively hold dot[lanen] (accd[lanen&3]) and
//   bias[lanen] (part[lanen&3], butterfly-complete in all lanes) -> 1 ds_bpermute, no LDS,
//   no syncs in the loop.
__global__ __launch_bounds__(256) void k_edge_mfma(
    const int* __restrict__ ei, const int* __restrict__ ej,
    const ushort_t* __restrict__ Qh, const ushort_t* __restrict__ Kh,
    const float* __restrict__ gate, const float* __restrict__ edge_vec,
    const float* __restrict__ W1, const float* __restrict__ b1,
    const float* __restrict__ W2, const float* __restrict__ b2,
    const float* __restrict__ W3, const float* __restrict__ b3,
    float* __restrict__ out4, int nEdges, long nTiles)
{
    // W1 columns, slot-swizzled (slot = d + (d>>3)) so the 4 q-group b128 reads
    // per instruction land in disjoint bank quads.
    __shared__ __align__(16) float4 sW1v[72];
    __shared__ float sB1[64];

    const int tid = threadIdx.x;
    const int lane = tid & 63;
    const int lanen = lane & 15;
    const int q = lane >> 4;
    const int w = tid >> 6;

    if (tid < 64) {
        int slot = tid + (tid >> 3);
        sW1v[slot] = make_float4(W1[tid], W1[64 + tid], W1[128 + tid], W1[192 + tid]);
        sB1[tid] = b1[tid];
    }

    bf16x8 Bfrag[2][4];
    #pragma unroll
    for (int c = 0; c < 2; ++c)
        #pragma unroll
        for (int t = 0; t < 4; ++t) {
            bf16x8 v;
            #pragma unroll
            for (int j = 0; j < 8; ++j)
                v[j] = (short)f2bf_fast(W2[(c * 32 + q * 8 + j) * 64 + t * 16 + lanen]);
            Bfrag[c][t] = v;
        }
    float b2r[4], w3r[4];
    #pragma unroll
    for (int t = 0; t < 4; ++t) { b2r[t] = b2[t * 16 + lanen]; w3r[t] = W3[t * 16 + lanen]; }
    const float b3r = b3[0];
    const int rsel = lanen & 3;
    const int bperm_addr = ((((lanen >> 2) << 4) | lanen) << 2);
    __syncthreads();

    const long wstride = (long)gridDim.x * 4;
    const long t0 = (long)blockIdx.x * 4 + w;

    auto idx_of = [&](long tile, int& ii, int& jj) {
        long es = tile * 16 + lanen;
        long esc = (es < nEdges) ? es : (long)(nEdges - 1);
        ii = ei[esc]; jj = ej[esc];
    };
    auto gather = [&](long tile, int ii, int jj,
                      bf16x8& A, bf16x8& B, bf16x8& C, bf16x8& D, float& G, float4& AT) {
        const bf16x8* qp = (const bf16x8*)(Qh + (size_t)jj * 64);
        A = qp[q]; B = qp[4 + q];
        const bf16x8* kp = (const bf16x8*)(Kh + (size_t)ii * 64);
        C = kp[q]; D = kp[4 + q];
        G = gate[ii];
        long em = tile * 16 + lanen;
        long emc = (em < nEdges) ? em : (long)(nEdges - 1);
        float ax = edge_vec[emc * 3 + 0];
        float ay = edge_vec[emc * 3 + 1];
        float az = edge_vec[emc * 3 + 2];
        AT = make_float4(ax, ay, az, sqrtf(ax * ax + ay * ay + az * az));
    };

    int iC, jC, iN, jN;
    idx_of(t0, iC, jC);
    idx_of(t0 + wstride, iN, jN);
    bf16x8 qa = {}, qb = {}, ka = {}, kb = {};
    float gte = 0.f;
    float4 attr = make_float4(0.f, 0.f, 0.f, 0.f);
    gather(t0, iC, jC, qa, qb, ka, kb, gte, attr);

    for (long tile = t0; tile < nTiles; tile += wstride) {
        // ---- layer1 directly into A-frag registers (fp32 math, RNE bf16 pack) ----
        int pw0[4], pw1[4];
        #pragma unroll
        for (int jj = 0; jj < 4; ++jj) {
            int d0 = q * 8 + 2 * jj;
            float4 cA = sW1v[d0 + q];
            float4 cB = sW1v[d0 + 1 + q];
            float4 cC = sW1v[d0 + 32 + q + 4];
            float4 cD = sW1v[d0 + 33 + q + 4];
            float p0 = sB1[d0]      + attr.x*cA.x + attr.y*cA.y + attr.z*cA.z + attr.w*cA.w;
            float p1 = sB1[d0 + 1]  + attr.x*cB.x + attr.y*cB.y + attr.z*cB.z + attr.w*cB.w;
            float p2 = sB1[d0 + 32] + attr.x*cC.x + attr.y*cC.y + attr.z*cC.z + attr.w*cC.w;
            float p3 = sB1[d0 + 33] + attr.x*cD.x + attr.y*cD.y + attr.z*cD.z + attr.w*cD.w;
            float h0 = silu_f(p0), h1v = silu_f(p1), h2v = silu_f(p2), h3v = silu_f(p3);
            int r0, r1;
            asm("v_cvt_pk_bf16_f32 %0, %1, %2" : "=v"(r0) : "v"(h0), "v"(h1v));
            asm("v_cvt_pk_bf16_f32 %0, %1, %2" : "=v"(r1) : "v"(h2v), "v"(h3v));
            pw0[jj] = r0; pw1[jj] = r1;
        }
        bf16x8 a0 = __builtin_bit_cast(bf16x8, make_int4(pw0[0], pw0[1], pw0[2], pw0[3]));
        bf16x8 a1 = __builtin_bit_cast(bf16x8, make_int4(pw1[0], pw1[1], pw1[2], pw1[3]));

        // ---- Q.K dot = diagonal of Q @ K^T via MFMA (matrix pipe is idle) ----
        f32x4 accd = {0.f, 0.f, 0.f, 0.f};
        accd = __builtin_amdgcn_mfma_f32_16x16x32_bf16(qa, ka, accd, 0, 0, 0);
        accd = __builtin_amdgcn_mfma_f32_16x16x32_bf16(qb, kb, accd, 0, 0, 0);

        // ---- layer2 GEMM ----
        f32x4 acc[4] = {{0,0,0,0},{0,0,0,0},{0,0,0,0},{0,0,0,0}};
        #pragma unroll
        for (int t = 0; t < 4; ++t) {
            acc[t] = __builtin_amdgcn_mfma_f32_16x16x32_bf16(a0, Bfrag[0][t], acc[t], 0, 0, 0);
            acc[t] = __builtin_amdgcn_mfma_f32_16x16x32_bf16(a1, Bfrag[1][t], acc[t], 0, 0, 0);
        }

        // ---- 1-ahead prefetch ----
        int iF, jF;
        idx_of(tile + 2 * wstride, iF, jF);
        bf16x8 qa2 = {}, qb2 = {}, ka2 = {}, kb2 = {};
        float gte2 = 0.f;
        float4 attr2 = make_float4(0.f, 0.f, 0.f, 0.f);
        gather(tile + wstride, iN, jN, qa2, qb2, ka2, kb2, gte2, attr2);

        // ---- layer3 reduce (butterfly -> all lanes hold part[r] for edges q*4+r) ----
        float part[4] = {0.f, 0.f, 0.f, 0.f};
        #pragma unroll
        for (int t = 0; t < 4; ++t)
            #pragma unroll
            for (int r = 0; r < 4; ++r)
                part[r] += silu_f(acc[t][r] + b2r[t]) * w3r[t];
        #pragma unroll
        for (int r = 0; r < 4; ++r) {
            part[r] += __shfl_xor(part[r], 1);
            part[r] += __shfl_xor(part[r], 2);
            part[r] += __shfl_xor(part[r], 4);
            part[r] += __shfl_xor(part[r], 8);
        }

        // ---- route dot+bias for edge lanen via one bpermute ----
        // source lane ((lanen>>2)<<4)|lanen has q==lanen>>2: accd[lanen&3] = dot[lanen],
        // part[lanen&3] = bias[lanen].
        float dsel = accd[0];
        dsel = (rsel == 1) ? accd[1] : dsel;
        dsel = (rsel == 2) ? accd[2] : dsel;
        dsel = (rsel == 3) ? accd[3] : dsel;
        float psel = part[0];
        psel = (rsel == 1) ? part[1] : psel;
        psel = (rsel == 2) ? part[2] : psel;
        psel = (rsel == 3) ? part[3] : psel;
        float val = fmaf(dsel, 0.125f, psel);
        int moved = __builtin_amdgcn_ds_bpermute(bperm_addr, __builtin_bit_cast(int, val));
        float sc = __builtin_bit_cast(float, moved) + b3r;

        // ---- max-free softmax numer/denom, fire-and-forget atomics ----
        float ev = __expf(sc);
        long eC = tile * 16 + lanen;
        if (eC < nEdges) {
            float comp = (q == 0) ? attr.x : (q == 1) ? attr.y : attr.z;
            float vout = (q == 3) ? ev : ev * gte * comp;
            atomicAdd(out4 + (size_t)jC * 4 + q, vout);
        }

        iC = iN; jC = jN; iN = iF; jN = jF;
        qa = qa2; qb = qb2; ka = ka2; kb = kb2; gte = gte2; attr = attr2;
    }
}

// ---------------- final divide: out = num / (den + 1e-16) ----------------
__global__ __launch_bounds__(256) void k_div(
    const float4* __restrict__ out4, float* __restrict__ out, int nNodes)
{
    int j = blockIdx.x * 256 + threadIdx.x;
    if (j >= nNodes) return;
    float4 v = out4[j];
    float inv = 1.0f / (v.w + 1e-16f);
    out[(size_t)j * 3 + 0] = v.x * inv;
    out[(size_t)j * 3 + 1] = v.y * inv;
    out[(size_t)j * 3 + 2] = v.z * inv;
}

extern "C" void kernel_launch(void* const* d_in, const int* in_sizes, int n_in,
                              void* d_out, int out_size, void* d_ws, size_t ws_size,
                              hipStream_t stream)
{
    const float* x        = (const float*)d_in[0];
    const float* edge_vec = (const float*)d_in[1];
    const float* Wq = (const float*)d_in[2];
    const float* bq = (const float*)d_in[3];
    const float* Wk = (const float*)d_in[4];
    const float* bk = (const float*)d_in[5];
    const float* Wv = (const float*)d_in[6];
    const float* bv = (const float*)d_in[7];
    const float* W1 = (const float*)d_in[8];
    const float* b1 = (const float*)d_in[9];
    const float* W2 = (const float*)d_in[10];
    const float* b2 = (const float*)d_in[11];
    const float* W3 = (const float*)d_in[12];
    const float* b3 = (const float*)d_in[13];
    const float* wF = (const float*)d_in[14];
    const float* bF = (const float*)d_in[15];
    const int*   eidx = (const int*)d_in[16];

    int nNodes = in_sizes[0] / DIM;
    int nEdges = in_sizes[16] / 2;
    const int* ei = eidx;
    const int* ej = eidx + nEdges;

    // ws layout
    char* p = (char*)d_ws;
    ushort_t* Qh = (ushort_t*)p;
    ushort_t* Kh = Qh + (size_t)nNodes * DIM;
    p += (size_t)nNodes * DIM * 2 * sizeof(ushort_t);
    float* gate = (float*)p;  p += (size_t)nNodes * sizeof(float);
    float* out4 = (float*)p;  p += (size_t)nNodes * 4 * sizeof(float);

    float* out = (float*)d_out;

    int nTilesN = (nNodes + 15) / 16;
    k_proj_mfma<<<1024, 256, 0, stream>>>(x, Wq, bq, Wk, bk, Wv, bv, wF, bF,
                                          Qh, Kh, gate, out4, nNodes, nTilesN);

    long nTilesE = (nEdges + 15) / 16;
    k_edge_mfma<<<2048, 256, 0, stream>>>(ei, ej, Qh, Kh, gate, edge_vec,
                                          W1, b1, W2, b2, W3, b3,
                                          out4, nEdges, nTilesE);

    int nBn = (nNodes + 255) / 256;
    k_div<<<nBn, 256, 0, stream>>>((const float4*)out4, out, nNodes);
}

// Round 3
// 233.323 us; speedup vs baseline: 1.2432x; 1.0281x over previous
//
#include <hip/hip_runtime.h>
#include <hip/hip_bf16.h>
#include <math.h>

#define DIM 64

typedef __attribute__((ext_vector_type(8))) short bf16x8;
typedef __attribute__((ext_vector_type(4))) float f32x4;
typedef __attribute__((ext_vector_type(2))) float f32x2;
typedef unsigned short ushort_t;

__device__ __forceinline__ float silu_f(float x) {
    float e = __expf(-x);
    return x * __builtin_amdgcn_rcpf(1.0f + e);
}
// fast fp32->bf16 RNE (finite inputs)
__device__ __forceinline__ unsigned short f2bf_fast(float x) {
    unsigned u = __builtin_bit_cast(unsigned, x);
    u += 0x7FFFu + ((u >> 16) & 1u);
    return (unsigned short)(u >> 16);
}
__device__ __forceinline__ unsigned cvtpk_bf16(float a, float b) {
    unsigned r;
    asm("v_cvt_pk_bf16_f32 %0, %1, %2" : "=v"(r) : "v"(a), "v"(b));
    return r;
}
// packed dual-fp32 math (CDNA4 VOP3P)
__device__ __forceinline__ f32x2 pk_fma2(f32x2 a, f32x2 b, f32x2 c) {
    f32x2 d;
    asm("v_pk_fma_f32 %0, %1, %2, %3" : "=v"(d) : "v"(a), "v"(b), "v"(c));
    return d;
}
__device__ __forceinline__ f32x2 pk_add2(f32x2 a, f32x2 b) {
    f32x2 d;
    asm("v_pk_add_f32 %0, %1, %2" : "=v"(d) : "v"(a), "v"(b));
    return d;
}
__device__ __forceinline__ f32x2 bc2(float x) { f32x2 r; r.x = x; r.y = x; return r; }
// butterfly add over lanen bits via ds_swizzle (0 VALU addr cost)
__device__ __forceinline__ float swz_add(float v, const int pat) {
    int iv = __builtin_bit_cast(int, v);
    int sv;
    switch (pat) {
        case 1: sv = __builtin_amdgcn_ds_swizzle(iv, 0x041F); break;
        case 2: sv = __builtin_amdgcn_ds_swizzle(iv, 0x081F); break;
        case 4: sv = __builtin_amdgcn_ds_swizzle(iv, 0x101F); break;
        default: sv = __builtin_amdgcn_ds_swizzle(iv, 0x201F); break;
    }
    return v + __builtin_bit_cast(float, sv);
}

// ---------------- k_proj: MFMA GEMM for Q, K (bf16 out) + gate + fused prep + out4 zero ----------------
// Operand-swapped MFMA: D[dim][node] so each lane owns ONE node and stores 8B chunks.
__global__ __launch_bounds__(256) void k_proj_mfma(
    const float* __restrict__ x,
    const float* __restrict__ Wq, const float* __restrict__ bq,
    const float* __restrict__ Wk, const float* __restrict__ bk,
    const float* __restrict__ Wv, const float* __restrict__ bv,
    const float* __restrict__ wF, const float* __restrict__ bF,
    ushort_t* __restrict__ Qh, ushort_t* __restrict__ Kh,
    float* __restrict__ gate, float* __restrict__ out4,
    int nNodes, int nTiles)
{
    const int tid = threadIdx.x;
    const int lane = tid & 63;
    const int w = tid >> 6;
    const int lanen = lane & 15;
    const int q = lane >> 4;

    // --- fused prep: u[d] = Wv[d,:]·wF (d = lane), c0 = bv·wF + bF ---
    float accu = 0.f;
    #pragma unroll
    for (int n = 0; n < 64; ++n) accu = fmaf(Wv[lane * 64 + n], wF[n], accu);
    float pc = bv[lane] * wF[lane];
    #pragma unroll
    for (int off = 32; off; off >>= 1) pc += __shfl_xor(pc, off, 64);
    const float c0 = pc + bF[0];
    const int ubits = __builtin_bit_cast(int, accu);
    float ur0[8], ur1[8];
    #pragma unroll
    for (int j = 0; j < 8; ++j) {
        ur0[j] = __builtin_bit_cast(float, __builtin_amdgcn_ds_bpermute((q * 8 + j) * 4, ubits));
        ur1[j] = __builtin_bit_cast(float, __builtin_amdgcn_ds_bpermute((32 + q * 8 + j) * 4, ubits));
    }

    bf16x8 Bq[2][4], Bk[2][4];
    #pragma unroll
    for (int c = 0; c < 2; ++c)
        #pragma unroll
        for (int t = 0; t < 4; ++t) {
            bf16x8 vq, vk;
            #pragma unroll
            for (int j = 0; j < 8; ++j) {
                int idx = (c * 32 + q * 8 + j) * 64 + t * 16 + lanen;
                vq[j] = (short)f2bf_fast(Wq[idx]);
                vk[j] = (short)f2bf_fast(Wk[idx]);
            }
            Bq[c][t] = vq; Bk[c][t] = vk;
        }
    // bias pairs for dims t*16 + q*4 + {0..3}
    const float4* bq4p = (const float4*)bq;
    const float4* bk4p = (const float4*)bk;
    float4 bq4[4], bk4[4];
    #pragma unroll
    for (int t = 0; t < 4; ++t) { bq4[t] = bq4p[t * 4 + q]; bk4[t] = bk4p[t * 4 + q]; }

    const int waveId = blockIdx.x * 4 + w;
    const int wstride = gridDim.x * 4;

    for (int tile = waveId; tile < nTiles; tile += wstride) {
        int node0 = tile * 16;
        int nodeA = node0 + lanen;
        int nodeC = (nodeA < nNodes) ? nodeA : (nNodes - 1);
        const float4* xr = (const float4*)(x + (size_t)nodeC * 64);
        float4 xa = xr[q * 2], xb = xr[q * 2 + 1];
        float4 xc = xr[8 + q * 2], xd = xr[8 + q * 2 + 1];

        float g = xa.x * ur0[0] + xa.y * ur0[1] + xa.z * ur0[2] + xa.w * ur0[3]
                + xb.x * ur0[4] + xb.y * ur0[5] + xb.z * ur0[6] + xb.w * ur0[7]
                + xc.x * ur1[0] + xc.y * ur1[1] + xc.z * ur1[2] + xc.w * ur1[3]
                + xd.x * ur1[4] + xd.y * ur1[5] + xd.z * ur1[6] + xd.w * ur1[7];
        g += __shfl_xor(g, 16);
        g += __shfl_xor(g, 32);

        bf16x8 a0, a1;
        a0[0] = (short)f2bf_fast(xa.x); a0[1] = (short)f2bf_fast(xa.y);
        a0[2] = (short)f2bf_fast(xa.z); a0[3] = (short)f2bf_fast(xa.w);
        a0[4] = (short)f2bf_fast(xb.x); a0[5] = (short)f2bf_fast(xb.y);
        a0[6] = (short)f2bf_fast(xb.z); a0[7] = (short)f2bf_fast(xb.w);
        a1[0] = (short)f2bf_fast(xc.x); a1[1] = (short)f2bf_fast(xc.y);
        a1[2] = (short)f2bf_fast(xc.z); a1[3] = (short)f2bf_fast(xc.w);
        a1[4] = (short)f2bf_fast(xd.x); a1[5] = (short)f2bf_fast(xd.y);
        a1[6] = (short)f2bf_fast(xd.z); a1[7] = (short)f2bf_fast(xd.w);

        f32x4 accq[4] = {{0,0,0,0},{0,0,0,0},{0,0,0,0},{0,0,0,0}};
        f32x4 acck[4] = {{0,0,0,0},{0,0,0,0},{0,0,0,0},{0,0,0,0}};
        __builtin_amdgcn_s_setprio(1);
        #pragma unroll
        for (int t = 0; t < 4; ++t) {
            // swapped operands: A = W-frag (rows = dims of tile t), B = x-frag (cols = nodes)
            accq[t] = __builtin_amdgcn_mfma_f32_16x16x32_bf16(Bq[0][t], a0, accq[t], 0, 0, 0);
            accq[t] = __builtin_amdgcn_mfma_f32_16x16x32_bf16(Bq[1][t], a1, accq[t], 0, 0, 0);
            acck[t] = __builtin_amdgcn_mfma_f32_16x16x32_bf16(Bk[0][t], a0, acck[t], 0, 0, 0);
            acck[t] = __builtin_amdgcn_mfma_f32_16x16x32_bf16(Bk[1][t], a1, acck[t], 0, 0, 0);
        }
        __builtin_amdgcn_s_setprio(0);

        // lane owns node = nodeA; holds dims t*16 + q*4 + r (r = reg)
        if (nodeA < nNodes) {
            ushort_t* qrow = Qh + (size_t)nodeA * 64 + q * 4;
            ushort_t* krow = Kh + (size_t)nodeA * 64 + q * 4;
            #pragma unroll
            for (int t = 0; t < 4; ++t) {
                f32x2 q01 = pk_add2((f32x2){accq[t][0], accq[t][1]}, (f32x2){bq4[t].x, bq4[t].y});
                f32x2 q23 = pk_add2((f32x2){accq[t][2], accq[t][3]}, (f32x2){bq4[t].z, bq4[t].w});
                uint2 pq;
                pq.x = cvtpk_bf16(q01.x, q01.y);
                pq.y = cvtpk_bf16(q23.x, q23.y);
                *(uint2*)(qrow + t * 16) = pq;
                f32x2 k01 = pk_add2((f32x2){acck[t][0], acck[t][1]}, (f32x2){bk4[t].x, bk4[t].y});
                f32x2 k23 = pk_add2((f32x2){acck[t][2], acck[t][3]}, (f32x2){bk4[t].z, bk4[t].w});
                uint2 pk;
                pk.x = cvtpk_bf16(k01.x, k01.y);
                pk.y = cvtpk_bf16(k23.x, k23.y);
                *(uint2*)(krow + t * 16) = pk;
            }
            if (q == 0) gate[nodeA] = g + c0;
            if (q == 1) *(float4*)(out4 + (size_t)nodeA * 4) = make_float4(0.f, 0.f, 0.f, 0.f);
        }
    }
}

// ---------------- edge kernel: MLP bias + MFMA score + atomic segment-sums ----------------
__global__ __launch_bounds__(256) void k_edge_mfma(
    const int* __restrict__ ei, const int* __restrict__ ej,
    const ushort_t* __restrict__ Qh, const ushort_t* __restrict__ Kh,
    const float* __restrict__ gate, const float* __restrict__ edge_vec,
    const float* __restrict__ W1, const float* __restrict__ b1,
    const float* __restrict__ W2, const float* __restrict__ b2,
    const float* __restrict__ W3, const float* __restrict__ b3,
    float* __restrict__ out4, int nEdges, long nTiles)
{
    // W1 stored as DIM-PAIR records for v_pk_fma_f32:
    //   logical index i = pair*2 + half (half 0: rows k=0,1; half 1: rows k=2,3)
    //   slot = i + (i>>3)  -> per-inst the 4 q-groups hit disjoint bank quads
    __shared__ __align__(16) float4 sW1x[72];
    __shared__ __align__(8) f32x2 sB1p[32];

    const int tid = threadIdx.x;
    const int lane = tid & 63;
    const int lanen = lane & 15;
    const int q = lane >> 4;
    const int w = tid >> 6;

    if (tid < 64) {
        int pp = tid >> 1, hh = tid & 1;
        int d0 = pp * 2, k0 = hh * 2;
        sW1x[tid + (tid >> 3)] = make_float4(
            W1[k0 * 64 + d0], W1[k0 * 64 + d0 + 1],
            W1[(k0 + 1) * 64 + d0], W1[(k0 + 1) * 64 + d0 + 1]);
    }
    if (tid < 32) {
        f32x2 bp; bp.x = b1[2 * tid]; bp.y = b1[2 * tid + 1];
        sB1p[tid] = bp;
    }

    bf16x8 Bfrag[2][4];
    #pragma unroll
    for (int c = 0; c < 2; ++c)
        #pragma unroll
        for (int t = 0; t < 4; ++t) {
            bf16x8 v;
            #pragma unroll
            for (int j = 0; j < 8; ++j)
                v[j] = (short)f2bf_fast(W2[(c * 32 + q * 8 + j) * 64 + t * 16 + lanen]);
            Bfrag[c][t] = v;
        }
    float b2r[4], w3r[4];
    f32x2 b2p[4];
    #pragma unroll
    for (int t = 0; t < 4; ++t) {
        b2r[t] = b2[t * 16 + lanen];
        w3r[t] = W3[t * 16 + lanen];
        b2p[t] = bc2(b2r[t]);
    }
    const float b3r = b3[0];
    const int rsel = lanen & 3;
    const int bperm_addr = ((((lanen >> 2) << 4) | lanen) << 2);
    const int slotA0 = q * 9;        // byte base handled by compiler via *16
    const int slotB0 = 36 + q * 9;
    __syncthreads();

    const long wstride = (long)gridDim.x * 4;
    const long t0 = (long)blockIdx.x * 4 + w;

    auto idx_of = [&](long tile, int& ii, int& jj) {
        long es = tile * 16 + lanen;
        long esc = (es < nEdges) ? es : (long)(nEdges - 1);
        ii = ei[esc]; jj = ej[esc];
    };
    auto gather = [&](long tile, int ii, int jj,
                      bf16x8& A, bf16x8& B, bf16x8& C, bf16x8& D, float& G, float4& AT) {
        const bf16x8* qp = (const bf16x8*)(Qh + (size_t)jj * 64);
        A = qp[q]; B = qp[4 + q];
        const bf16x8* kp = (const bf16x8*)(Kh + (size_t)ii * 64);
        C = kp[q]; D = kp[4 + q];
        G = gate[ii];
        long em = tile * 16 + lanen;
        long emc = (em < nEdges) ? em : (long)(nEdges - 1);
        float ax = edge_vec[emc * 3 + 0];
        float ay = edge_vec[emc * 3 + 1];
        float az = edge_vec[emc * 3 + 2];
        AT = make_float4(ax, ay, az, sqrtf(ax * ax + ay * ay + az * az));
    };

    int iC, jC, iN, jN;
    idx_of(t0, iC, jC);
    idx_of(t0 + wstride, iN, jN);
    bf16x8 qa = {}, qb = {}, ka = {}, kb = {};
    float gte = 0.f;
    float4 attr = make_float4(0.f, 0.f, 0.f, 0.f);
    gather(t0, iC, jC, qa, qb, ka, kb, gte, attr);

    for (long tile = t0; tile < nTiles; tile += wstride) {
        // ---- layer1 in A-frag layout, packed fp32 FMAs ----
        f32x2 ax2 = bc2(attr.x), ay2 = bc2(attr.y), az2 = bc2(attr.z), aw2 = bc2(attr.w);
        int pw0[4], pw1[4];
        #pragma unroll
        for (int s = 0; s < 4; ++s) {
            // pair A: dims q*8+2s, q*8+2s+1
            float4 wa0 = sW1x[slotA0 + 2 * s];
            float4 wa1 = sW1x[slotA0 + 2 * s + 1];
            f32x2 hA = sB1p[q * 4 + s];
            hA = pk_fma2((f32x2){wa0.x, wa0.y}, ax2, hA);
            hA = pk_fma2((f32x2){wa0.z, wa0.w}, ay2, hA);
            hA = pk_fma2((f32x2){wa1.x, wa1.y}, az2, hA);
            hA = pk_fma2((f32x2){wa1.z, wa1.w}, aw2, hA);
            // pair B: dims 32+q*8+2s, +1
            float4 wb0 = sW1x[slotB0 + 2 * s];
            float4 wb1 = sW1x[slotB0 + 2 * s + 1];
            f32x2 hB = sB1p[16 + q * 4 + s];
            hB = pk_fma2((f32x2){wb0.x, wb0.y}, ax2, hB);
            hB = pk_fma2((f32x2){wb0.z, wb0.w}, ay2, hB);
            hB = pk_fma2((f32x2){wb1.x, wb1.y}, az2, hB);
            hB = pk_fma2((f32x2){wb1.z, wb1.w}, aw2, hB);
            pw0[s] = (int)cvtpk_bf16(silu_f(hA.x), silu_f(hA.y));
            pw1[s] = (int)cvtpk_bf16(silu_f(hB.x), silu_f(hB.y));
        }
        bf16x8 a0 = __builtin_bit_cast(bf16x8, make_int4(pw0[0], pw0[1], pw0[2], pw0[3]));
        bf16x8 a1 = __builtin_bit_cast(bf16x8, make_int4(pw1[0], pw1[1], pw1[2], pw1[3]));

        // ---- MFMA cluster: QK diag + layer2 GEMM ----
        __builtin_amdgcn_s_setprio(1);
        f32x4 accd = {0.f, 0.f, 0.f, 0.f};
        accd = __builtin_amdgcn_mfma_f32_16x16x32_bf16(qa, ka, accd, 0, 0, 0);
        accd = __builtin_amdgcn_mfma_f32_16x16x32_bf16(qb, kb, accd, 0, 0, 0);
        f32x4 acc[4] = {{0,0,0,0},{0,0,0,0},{0,0,0,0},{0,0,0,0}};
        #pragma unroll
        for (int t = 0; t < 4; ++t) {
            acc[t] = __builtin_amdgcn_mfma_f32_16x16x32_bf16(a0, Bfrag[0][t], acc[t], 0, 0, 0);
            acc[t] = __builtin_amdgcn_mfma_f32_16x16x32_bf16(a1, Bfrag[1][t], acc[t], 0, 0, 0);
        }
        __builtin_amdgcn_s_setprio(0);

        // ---- 1-ahead prefetch ----
        int iF, jF;
        idx_of(tile + 2 * wstride, iF, jF);
        bf16x8 qa2 = {}, qb2 = {}, ka2 = {}, kb2 = {};
        float gte2 = 0.f;
        float4 attr2 = make_float4(0.f, 0.f, 0.f, 0.f);
        gather(tile + wstride, iN, jN, qa2, qb2, ka2, kb2, gte2, attr2);

        // ---- layer3: packed bias-add, scalar silu, butterfly via ds_swizzle ----
        float part[4] = {0.f, 0.f, 0.f, 0.f};
        #pragma unroll
        for (int t = 0; t < 4; ++t) {
            f32x2 s01 = pk_add2((f32x2){acc[t][0], acc[t][1]}, b2p[t]);
            f32x2 s23 = pk_add2((f32x2){acc[t][2], acc[t][3]}, b2p[t]);
            part[0] = fmaf(silu_f(s01.x), w3r[t], part[0]);
            part[1] = fmaf(silu_f(s01.y), w3r[t], part[1]);
            part[2] = fmaf(silu_f(s23.x), w3r[t], part[2]);
            part[3] = fmaf(silu_f(s23.y), w3r[t], part[3]);
        }
        #pragma unroll
        for (int r = 0; r < 4; ++r) {
            part[r] = swz_add(part[r], 1);
            part[r] = swz_add(part[r], 2);
            part[r] = swz_add(part[r], 4);
            part[r] = swz_add(part[r], 8);
        }

        // ---- route dot+bias for edge lanen via one bpermute ----
        float dsel = accd[0];
        dsel = (rsel == 1) ? accd[1] : dsel;
        dsel = (rsel == 2) ? accd[2] : dsel;
        dsel = (rsel == 3) ? accd[3] : dsel;
        float psel = part[0];
        psel = (rsel == 1) ? part[1] : psel;
        psel = (rsel == 2) ? part[2] : psel;
        psel = (rsel == 3) ? part[3] : psel;
        float val = fmaf(dsel, 0.125f, psel);
        int moved = __builtin_amdgcn_ds_bpermute(bperm_addr, __builtin_bit_cast(int, val));
        float sc = __builtin_bit_cast(float, moved) + b3r;

        // ---- max-free softmax numer/denom, fire-and-forget atomics ----
        float ev = __expf(sc);
        long eC = tile * 16 + lanen;
        if (eC < nEdges) {
            float comp = (q == 0) ? attr.x : (q == 1) ? attr.y : attr.z;
            float vout = (q == 3) ? ev : ev * gte * comp;
            atomicAdd(out4 + (size_t)jC * 4 + q, vout);
        }

        iC = iN; jC = jN; iN = iF; jN = jF;
        qa = qa2; qb = qb2; ka = ka2; kb = kb2; gte = gte2; attr = attr2;
    }
}

// ---------------- final divide: out = num / (den + 1e-16) ----------------
__global__ __launch_bounds__(256) void k_div(
    const float4* __restrict__ out4, float* __restrict__ out, int nNodes)
{
    int j = blockIdx.x * 256 + threadIdx.x;
    if (j >= nNodes) return;
    float4 v = out4[j];
    float inv = 1.0f / (v.w + 1e-16f);
    out[(size_t)j * 3 + 0] = v.x * inv;
    out[(size_t)j * 3 + 1] = v.y * inv;
    out[(size_t)j * 3 + 2] = v.z * inv;
}

extern "C" void kernel_launch(void* const* d_in, const int* in_sizes, int n_in,
                              void* d_out, int out_size, void* d_ws, size_t ws_size,
                              hipStream_t stream)
{
    const float* x        = (const float*)d_in[0];
    const float* edge_vec = (const float*)d_in[1];
    const float* Wq = (const float*)d_in[2];
    const float* bq = (const float*)d_in[3];
    const float* Wk = (const float*)d_in[4];
    const float* bk = (const float*)d_in[5];
    const float* Wv = (const float*)d_in[6];
    const float* bv = (const float*)d_in[7];
    const float* W1 = (const float*)d_in[8];
    const float* b1 = (const float*)d_in[9];
    const float* W2 = (const float*)d_in[10];
    const float* b2 = (const float*)d_in[11];
    const float* W3 = (const float*)d_in[12];
    const float* b3 = (const float*)d_in[13];
    const float* wF = (const float*)d_in[14];
    const float* bF = (const float*)d_in[15];
    const int*   eidx = (const int*)d_in[16];

    int nNodes = in_sizes[0] / DIM;
    int nEdges = in_sizes[16] / 2;
    const int* ei = eidx;
    const int* ej = eidx + nEdges;

    // ws layout
    char* p = (char*)d_ws;
    ushort_t* Qh = (ushort_t*)p;
    ushort_t* Kh = Qh + (size_t)nNodes * DIM;
    p += (size_t)nNodes * DIM * 2 * sizeof(ushort_t);
    float* gate = (float*)p;  p += (size_t)nNodes * sizeof(float);
    float* out4 = (float*)p;  p += (size_t)nNodes * 4 * sizeof(float);

    float* out = (float*)d_out;

    int nTilesN = (nNodes + 15) / 16;
    k_proj_mfma<<<1024, 256, 0, stream>>>(x, Wq, bq, Wk, bk, Wv, bv, wF, bF,
                                          Qh, Kh, gate, out4, nNodes, nTilesN);

    long nTilesE = (nEdges + 15) / 16;
    k_edge_mfma<<<2048, 256, 0, stream>>>(ei, ej, Qh, Kh, gate, edge_vec,
                                          W1, b1, W2, b2, W3, b3,
                                          out4, nEdges, nTilesE);

    int nBn = (nNodes + 255) / 256;
    k_div<<<nBn, 256, 0, stream>>>((const float4*)out4, out, nNodes);
}

// Round 5
// 225.554 us; speedup vs baseline: 1.2860x; 1.0344x over previous
//
#include <hip/hip_runtime.h>
#include <hip/hip_bf16.h>
#include <math.h>

#define DIM 64

typedef __attribute__((ext_vector_type(8))) short bf16x8;
typedef __attribute__((ext_vector_type(4))) float f32x4;
typedef __attribute__((ext_vector_type(2))) float f32x2;
typedef unsigned short ushort_t;

__device__ __forceinline__ float silu_f(float x) {
    float e = __expf(-x);
    return x * __builtin_amdgcn_rcpf(1.0f + e);
}
// fast fp32->bf16 RNE (finite inputs)
__device__ __forceinline__ unsigned short f2bf_fast(float x) {
    unsigned u = __builtin_bit_cast(unsigned, x);
    u += 0x7FFFu + ((u >> 16) & 1u);
    return (unsigned short)(u >> 16);
}
__device__ __forceinline__ unsigned cvtpk_bf16(float a, float b) {
    unsigned r;
    asm("v_cvt_pk_bf16_f32 %0, %1, %2" : "=v"(r) : "v"(a), "v"(b));
    return r;
}
// packed dual-fp32 math (CDNA4 VOP3P)
__device__ __forceinline__ f32x2 pk_fma2(f32x2 a, f32x2 b, f32x2 c) {
    f32x2 d;
    asm("v_pk_fma_f32 %0, %1, %2, %3" : "=v"(d) : "v"(a), "v"(b), "v"(c));
    return d;
}
__device__ __forceinline__ f32x2 pk_add2(f32x2 a, f32x2 b) {
    f32x2 d;
    asm("v_pk_add_f32 %0, %1, %2" : "=v"(d) : "v"(a), "v"(b));
    return d;
}
__device__ __forceinline__ f32x2 bc2(float x) { f32x2 r; r.x = x; r.y = x; return r; }
// butterfly add over lane bits via ds_swizzle (0 VALU addr cost)
__device__ __forceinline__ float swz_add(float v, const int pat) {
    int iv = __builtin_bit_cast(int, v);
    int sv;
    switch (pat) {
        case 1: sv = __builtin_amdgcn_ds_swizzle(iv, 0x041F); break;
        case 2: sv = __builtin_amdgcn_ds_swizzle(iv, 0x081F); break;
        case 4: sv = __builtin_amdgcn_ds_swizzle(iv, 0x101F); break;
        default: sv = __builtin_amdgcn_ds_swizzle(iv, 0x201F); break;
    }
    return v + __builtin_bit_cast(float, sv);
}

// ---------------- k_proj: MFMA GEMM for Q, K (bf16 out) + gate + fused prep + out4 zero ----------------
// Operand-swapped MFMA: D[dim][node] so each lane owns ONE node and stores 8B chunks.
// Prep (u = Wv·wF, c0) computed once per BLOCK by wave 0 with float4 row loads,
// broadcast via LDS (was: per-wave stride-64 scalar loads = ~1GB of L2 line traffic).
__global__ __launch_bounds__(256) void k_proj_mfma(
    const float* __restrict__ x,
    const float* __restrict__ Wq, const float* __restrict__ bq,
    const float* __restrict__ Wk, const float* __restrict__ bk,
    const float* __restrict__ Wv, const float* __restrict__ bv,
    const float* __restrict__ wF, const float* __restrict__ bF,
    ushort_t* __restrict__ Qh, ushort_t* __restrict__ Kh,
    float* __restrict__ gate, float* __restrict__ out4,
    int nNodes, int nTiles)
{
    __shared__ float sU[64];
    __shared__ float sC0;

    const int tid = threadIdx.x;
    const int lane = tid & 63;
    const int w = tid >> 6;
    const int lanen = lane & 15;
    const int q = lane >> 4;

    // --- fused prep (wave 0 only): u[d] = Wv[d,:]·wF ; c0 = bv·wF + bF ---
    if (tid < 64) {
        const float4* wvr = (const float4*)(Wv + (size_t)lane * 64);
        float accu = 0.f;
        #pragma unroll
        for (int n4 = 0; n4 < 16; ++n4) {
            float4 wv = wvr[n4];
            accu = fmaf(wv.x, wF[n4 * 4 + 0], accu);
            accu = fmaf(wv.y, wF[n4 * 4 + 1], accu);
            accu = fmaf(wv.z, wF[n4 * 4 + 2], accu);
            accu = fmaf(wv.w, wF[n4 * 4 + 3], accu);
        }
        sU[lane] = accu;
        float pc = bv[lane] * wF[lane];
        #pragma unroll
        for (int off = 32; off; off >>= 1) pc += __shfl_xor(pc, off, 64);
        if (lane == 0) sC0 = pc + bF[0];
    }

    bf16x8 Bq[2][4], Bk[2][4];
    #pragma unroll
    for (int c = 0; c < 2; ++c)
        #pragma unroll
        for (int t = 0; t < 4; ++t) {
            bf16x8 vq, vk;
            #pragma unroll
            for (int j = 0; j < 8; ++j) {
                int idx = (c * 32 + q * 8 + j) * 64 + t * 16 + lanen;
                vq[j] = (short)f2bf_fast(Wq[idx]);
                vk[j] = (short)f2bf_fast(Wk[idx]);
            }
            Bq[c][t] = vq; Bk[c][t] = vk;
        }
    // bias pairs for dims t*16 + q*4 + {0..3}
    const float4* bq4p = (const float4*)bq;
    const float4* bk4p = (const float4*)bk;
    float4 bq4[4], bk4[4];
    #pragma unroll
    for (int t = 0; t < 4; ++t) { bq4[t] = bq4p[t * 4 + q]; bk4[t] = bk4p[t * 4 + q]; }

    __syncthreads();
    const float c0 = sC0;
    float ur0[8], ur1[8];
    #pragma unroll
    for (int j = 0; j < 8; ++j) { ur0[j] = sU[q * 8 + j]; ur1[j] = sU[32 + q * 8 + j]; }

    const int waveId = blockIdx.x * 4 + w;
    const int wstride = gridDim.x * 4;

    for (int tile = waveId; tile < nTiles; tile += wstride) {
        int node0 = tile * 16;
        int nodeA = node0 + lanen;
        int nodeC = (nodeA < nNodes) ? nodeA : (nNodes - 1);
        const float4* xr = (const float4*)(x + (size_t)nodeC * 64);
        float4 xa = xr[q * 2], xb = xr[q * 2 + 1];
        float4 xc = xr[8 + q * 2], xd = xr[8 + q * 2 + 1];

        float g = xa.x * ur0[0] + xa.y * ur0[1] + xa.z * ur0[2] + xa.w * ur0[3]
                + xb.x * ur0[4] + xb.y * ur0[5] + xb.z * ur0[6] + xb.w * ur0[7]
                + xc.x * ur1[0] + xc.y * ur1[1] + xc.z * ur1[2] + xc.w * ur1[3]
                + xd.x * ur1[4] + xd.y * ur1[5] + xd.z * ur1[6] + xd.w * ur1[7];
        g += __shfl_xor(g, 16);
        g += __shfl_xor(g, 32);

        bf16x8 a0, a1;
        a0[0] = (short)f2bf_fast(xa.x); a0[1] = (short)f2bf_fast(xa.y);
        a0[2] = (short)f2bf_fast(xa.z); a0[3] = (short)f2bf_fast(xa.w);
        a0[4] = (short)f2bf_fast(xb.x); a0[5] = (short)f2bf_fast(xb.y);
        a0[6] = (short)f2bf_fast(xb.z); a0[7] = (short)f2bf_fast(xb.w);
        a1[0] = (short)f2bf_fast(xc.x); a1[1] = (short)f2bf_fast(xc.y);
        a1[2] = (short)f2bf_fast(xc.z); a1[3] = (short)f2bf_fast(xc.w);
        a1[4] = (short)f2bf_fast(xd.x); a1[5] = (short)f2bf_fast(xd.y);
        a1[6] = (short)f2bf_fast(xd.z); a1[7] = (short)f2bf_fast(xd.w);

        f32x4 accq[4] = {{0,0,0,0},{0,0,0,0},{0,0,0,0},{0,0,0,0}};
        f32x4 acck[4] = {{0,0,0,0},{0,0,0,0},{0,0,0,0},{0,0,0,0}};
        __builtin_amdgcn_s_setprio(1);
        #pragma unroll
        for (int t = 0; t < 4; ++t) {
            // swapped operands: A = W-frag (rows = dims of tile t), B = x-frag (cols = nodes)
            accq[t] = __builtin_amdgcn_mfma_f32_16x16x32_bf16(Bq[0][t], a0, accq[t], 0, 0, 0);
            accq[t] = __builtin_amdgcn_mfma_f32_16x16x32_bf16(Bq[1][t], a1, accq[t], 0, 0, 0);
            acck[t] = __builtin_amdgcn_mfma_f32_16x16x32_bf16(Bk[0][t], a0, acck[t], 0, 0, 0);
            acck[t] = __builtin_amdgcn_mfma_f32_16x16x32_bf16(Bk[1][t], a1, acck[t], 0, 0, 0);
        }
        __builtin_amdgcn_s_setprio(0);

        // lane owns node = nodeA; holds dims t*16 + q*4 + r (r = reg)
        if (nodeA < nNodes) {
            ushort_t* qrow = Qh + (size_t)nodeA * 64 + q * 4;
            ushort_t* krow = Kh + (size_t)nodeA * 64 + q * 4;
            #pragma unroll
            for (int t = 0; t < 4; ++t) {
                f32x2 q01 = pk_add2((f32x2){accq[t][0], accq[t][1]}, (f32x2){bq4[t].x, bq4[t].y});
                f32x2 q23 = pk_add2((f32x2){accq[t][2], accq[t][3]}, (f32x2){bq4[t].z, bq4[t].w});
                uint2 pq;
                pq.x = cvtpk_bf16(q01.x, q01.y);
                pq.y = cvtpk_bf16(q23.x, q23.y);
                *(uint2*)(qrow + t * 16) = pq;
                f32x2 k01 = pk_add2((f32x2){acck[t][0], acck[t][1]}, (f32x2){bk4[t].x, bk4[t].y});
                f32x2 k23 = pk_add2((f32x2){acck[t][2], acck[t][3]}, (f32x2){bk4[t].z, bk4[t].w});
                uint2 pk;
                pk.x = cvtpk_bf16(k01.x, k01.y);
                pk.y = cvtpk_bf16(k23.x, k23.y);
                *(uint2*)(krow + t * 16) = pk;
            }
            if (q == 0) gate[nodeA] = g + c0;
            if (q == 1) *(float4*)(out4 + (size_t)nodeA * 4) = make_float4(0.f, 0.f, 0.f, 0.f);
        }
    }
}

// ---------------- edge kernel: MLP bias + MFMA score + atomic segment-sums ----------------
// (exact round-3 known-good version)
__global__ __launch_bounds__(256) void k_edge_mfma(
    const int* __restrict__ ei, const int* __restrict__ ej,
    const ushort_t* __restrict__ Qh, const ushort_t* __restrict__ Kh,
    const float* __restrict__ gate, const float* __restrict__ edge_vec,
    const float* __restrict__ W1, const float* __restrict__ b1,
    const float* __restrict__ W2, const float* __restrict__ b2,
    const float* __restrict__ W3, const float* __restrict__ b3,
    float* __restrict__ out4, int nEdges, long nTiles)
{
    // W1 pair records for v_pk_fma_f32, slot-swizzled (i + (i>>3)) for bank spread.
    __shared__ __align__(16) float4 sW1x[72];
    __shared__ __align__(8) f32x2 sB1p[32];

    const int tid = threadIdx.x;
    const int lane = tid & 63;
    const int lanen = lane & 15;
    const int q = lane >> 4;
    const int w = tid >> 6;

    if (tid < 64) {
        int pp = tid >> 1, hh = tid & 1;
        int d0 = pp * 2, k0 = hh * 2;
        sW1x[tid + (tid >> 3)] = make_float4(
            W1[k0 * 64 + d0], W1[k0 * 64 + d0 + 1],
            W1[(k0 + 1) * 64 + d0], W1[(k0 + 1) * 64 + d0 + 1]);
    }
    if (tid < 32) {
        f32x2 bp; bp.x = b1[2 * tid]; bp.y = b1[2 * tid + 1];
        sB1p[tid] = bp;
    }

    bf16x8 Bfrag[2][4];
    #pragma unroll
    for (int c = 0; c < 2; ++c)
        #pragma unroll
        for (int t = 0; t < 4; ++t) {
            bf16x8 v;
            #pragma unroll
            for (int j = 0; j < 8; ++j)
                v[j] = (short)f2bf_fast(W2[(c * 32 + q * 8 + j) * 64 + t * 16 + lanen]);
            Bfrag[c][t] = v;
        }
    float b2r[4], w3r[4];
    f32x2 b2p[4];
    #pragma unroll
    for (int t = 0; t < 4; ++t) {
        b2r[t] = b2[t * 16 + lanen];
        w3r[t] = W3[t * 16 + lanen];
        b2p[t] = bc2(b2r[t]);
    }
    const float b3r = b3[0];
    const int rsel = lanen & 3;
    const int bperm_addr = ((((lanen >> 2) << 4) | lanen) << 2);
    const int slotA0 = q * 9;
    const int slotB0 = 36 + q * 9;
    __syncthreads();

    const long wstride = (long)gridDim.x * 4;
    const long t0 = (long)blockIdx.x * 4 + w;

    auto idx_of = [&](long tile, int& ii, int& jj) {
        long es = tile * 16 + lanen;
        long esc = (es < nEdges) ? es : (long)(nEdges - 1);
        ii = ei[esc]; jj = ej[esc];
    };
    auto gather = [&](long tile, int ii, int jj,
                      bf16x8& A, bf16x8& B, bf16x8& C, bf16x8& D, float& G, float4& AT) {
        const bf16x8* qp = (const bf16x8*)(Qh + (size_t)jj * 64);
        A = qp[q]; B = qp[4 + q];
        const bf16x8* kp = (const bf16x8*)(Kh + (size_t)ii * 64);
        C = kp[q]; D = kp[4 + q];
        G = gate[ii];
        long em = tile * 16 + lanen;
        long emc = (em < nEdges) ? em : (long)(nEdges - 1);
        float ax = edge_vec[emc * 3 + 0];
        float ay = edge_vec[emc * 3 + 1];
        float az = edge_vec[emc * 3 + 2];
        AT = make_float4(ax, ay, az, sqrtf(ax * ax + ay * ay + az * az));
    };

    int iC, jC, iN, jN;
    idx_of(t0, iC, jC);
    idx_of(t0 + wstride, iN, jN);
    bf16x8 qa = {}, qb = {}, ka = {}, kb = {};
    float gte = 0.f;
    float4 attr = make_float4(0.f, 0.f, 0.f, 0.f);
    gather(t0, iC, jC, qa, qb, ka, kb, gte, attr);

    for (long tile = t0; tile < nTiles; tile += wstride) {
        // ---- layer1 in A-frag layout, packed fp32 FMAs ----
        f32x2 ax2 = bc2(attr.x), ay2 = bc2(attr.y), az2 = bc2(attr.z), aw2 = bc2(attr.w);
        int pw0[4], pw1[4];
        #pragma unroll
        for (int s = 0; s < 4; ++s) {
            float4 wa0 = sW1x[slotA0 + 2 * s];
            float4 wa1 = sW1x[slotA0 + 2 * s + 1];
            f32x2 hA = sB1p[q * 4 + s];
            hA = pk_fma2((f32x2){wa0.x, wa0.y}, ax2, hA);
            hA = pk_fma2((f32x2){wa0.z, wa0.w}, ay2, hA);
            hA = pk_fma2((f32x2){wa1.x, wa1.y}, az2, hA);
            hA = pk_fma2((f32x2){wa1.z, wa1.w}, aw2, hA);
            float4 wb0 = sW1x[slotB0 + 2 * s];
            float4 wb1 = sW1x[slotB0 + 2 * s + 1];
            f32x2 hB = sB1p[16 + q * 4 + s];
            hB = pk_fma2((f32x2){wb0.x, wb0.y}, ax2, hB);
            hB = pk_fma2((f32x2){wb0.z, wb0.w}, ay2, hB);
            hB = pk_fma2((f32x2){wb1.x, wb1.y}, az2, hB);
            hB = pk_fma2((f32x2){wb1.z, wb1.w}, aw2, hB);
            pw0[s] = (int)cvtpk_bf16(silu_f(hA.x), silu_f(hA.y));
            pw1[s] = (int)cvtpk_bf16(silu_f(hB.x), silu_f(hB.y));
        }
        bf16x8 a0 = __builtin_bit_cast(bf16x8, make_int4(pw0[0], pw0[1], pw0[2], pw0[3]));
        bf16x8 a1 = __builtin_bit_cast(bf16x8, make_int4(pw1[0], pw1[1], pw1[2], pw1[3]));

        // ---- MFMA cluster: QK diag + layer2 GEMM ----
        __builtin_amdgcn_s_setprio(1);
        f32x4 accd = {0.f, 0.f, 0.f, 0.f};
        accd = __builtin_amdgcn_mfma_f32_16x16x32_bf16(qa, ka, accd, 0, 0, 0);
        accd = __builtin_amdgcn_mfma_f32_16x16x32_bf16(qb, kb, accd, 0, 0, 0);
        f32x4 acc[4] = {{0,0,0,0},{0,0,0,0},{0,0,0,0},{0,0,0,0}};
        #pragma unroll
        for (int t = 0; t < 4; ++t) {
            acc[t] = __builtin_amdgcn_mfma_f32_16x16x32_bf16(a0, Bfrag[0][t], acc[t], 0, 0, 0);
            acc[t] = __builtin_amdgcn_mfma_f32_16x16x32_bf16(a1, Bfrag[1][t], acc[t], 0, 0, 0);
        }
        __builtin_amdgcn_s_setprio(0);

        // ---- 1-ahead prefetch ----
        int iF, jF;
        idx_of(tile + 2 * wstride, iF, jF);
        bf16x8 qa2 = {}, qb2 = {}, ka2 = {}, kb2 = {};
        float gte2 = 0.f;
        float4 attr2 = make_float4(0.f, 0.f, 0.f, 0.f);
        gather(tile + wstride, iN, jN, qa2, qb2, ka2, kb2, gte2, attr2);

        // ---- layer3: packed bias-add, scalar silu, butterfly via ds_swizzle ----
        float part[4] = {0.f, 0.f, 0.f, 0.f};
        #pragma unroll
        for (int t = 0; t < 4; ++t) {
            f32x2 s01 = pk_add2((f32x2){acc[t][0], acc[t][1]}, b2p[t]);
            f32x2 s23 = pk_add2((f32x2){acc[t][2], acc[t][3]}, b2p[t]);
            part[0] = fmaf(silu_f(s01.x), w3r[t], part[0]);
            part[1] = fmaf(silu_f(s01.y), w3r[t], part[1]);
            part[2] = fmaf(silu_f(s23.x), w3r[t], part[2]);
            part[3] = fmaf(silu_f(s23.y), w3r[t], part[3]);
        }
        #pragma unroll
        for (int r = 0; r < 4; ++r) {
            part[r] = swz_add(part[r], 1);
            part[r] = swz_add(part[r], 2);
            part[r] = swz_add(part[r], 4);
            part[r] = swz_add(part[r], 8);
        }

        // ---- route dot+bias for edge lanen via one bpermute ----
        float dsel = accd[0];
        dsel = (rsel == 1) ? accd[1] : dsel;
        dsel = (rsel == 2) ? accd[2] : dsel;
        dsel = (rsel == 3) ? accd[3] : dsel;
        float psel = part[0];
        psel = (rsel == 1) ? part[1] : psel;
        psel = (rsel == 2) ? part[2] : psel;
        psel = (rsel == 3) ? part[3] : psel;
        float val = fmaf(dsel, 0.125f, psel);
        int moved = __builtin_amdgcn_ds_bpermute(bperm_addr, __builtin_bit_cast(int, val));
        float sc = __builtin_bit_cast(float, moved) + b3r;

        // ---- max-free softmax numer/denom, fire-and-forget atomics ----
        float ev = __expf(sc);
        long eC = tile * 16 + lanen;
        if (eC < nEdges) {
            float comp = (q == 0) ? attr.x : (q == 1) ? attr.y : attr.z;
            float vout = (q == 3) ? ev : ev * gte * comp;
            atomicAdd(out4 + (size_t)jC * 4 + q, vout);
        }

        iC = iN; jC = jN; iN = iF; jN = jF;
        qa = qa2; qb = qb2; ka = ka2; kb = kb2; gte = gte2; attr = attr2;
    }
}

// ---------------- final divide: out = num / (den + 1e-16) ----------------
__global__ __launch_bounds__(256) void k_div(
    const float4* __restrict__ out4, float* __restrict__ out, int nNodes)
{
    int j = blockIdx.x * 256 + threadIdx.x;
    if (j >= nNodes) return;
    float4 v = out4[j];
    float inv = 1.0f / (v.w + 1e-16f);
    out[(size_t)j * 3 + 0] = v.x * inv;
    out[(size_t)j * 3 + 1] = v.y * inv;
    out[(size_t)j * 3 + 2] = v.z * inv;
}

extern "C" void kernel_launch(void* const* d_in, const int* in_sizes, int n_in,
                              void* d_out, int out_size, void* d_ws, size_t ws_size,
                              hipStream_t stream)
{
    const float* x        = (const float*)d_in[0];
    const float* edge_vec = (const float*)d_in[1];
    const float* Wq = (const float*)d_in[2];
    const float* bq = (const float*)d_in[3];
    const float* Wk = (const float*)d_in[4];
    const float* bk = (const float*)d_in[5];
    const float* Wv = (const float*)d_in[6];
    const float* bv = (const float*)d_in[7];
    const float* W1 = (const float*)d_in[8];
    const float* b1 = (const float*)d_in[9];
    const float* W2 = (const float*)d_in[10];
    const float* b2 = (const float*)d_in[11];
    const float* W3 = (const float*)d_in[12];
    const float* b3 = (const float*)d_in[13];
    const float* wF = (const float*)d_in[14];
    const float* bF = (const float*)d_in[15];
    const int*   eidx = (const int*)d_in[16];

    int nNodes = in_sizes[0] / DIM;
    int nEdges = in_sizes[16] / 2;
    const int* ei = eidx;
    const int* ej = eidx + nEdges;

    // ws layout
    char* p = (char*)d_ws;
    ushort_t* Qh = (ushort_t*)p;
    ushort_t* Kh = Qh + (size_t)nNodes * DIM;
    p += (size_t)nNodes * DIM * 2 * sizeof(ushort_t);
    float* gate = (float*)p;  p += (size_t)nNodes * sizeof(float);
    float* out4 = (float*)p;  p += (size_t)nNodes * 4 * sizeof(float);

    float* out = (float*)d_out;

    int nTilesN = (nNodes + 15) / 16;
    k_proj_mfma<<<1024, 256, 0, stream>>>(x, Wq, bq, Wk, bk, Wv, bv, wF, bF,
                                          Qh, Kh, gate, out4, nNodes, nTilesN);

    long nTilesE = (nEdges + 15) / 16;
    k_edge_mfma<<<2048, 256, 0, stream>>>(ei, ej, Qh, Kh, gate, edge_vec,
                                          W1, b1, W2, b2, W3, b3,
                                          out4, nEdges, nTilesE);

    int nBn = (nNodes + 255) / 256;
    k_div<<<nBn, 256, 0, stream>>>((const float4*)out4, out, nNodes);
}